// Round 17
// baseline (256.397 us; speedup 1.0000x reference)
//
#include <hip/hip_runtime.h>
#include <hip/hip_bf16.h>

typedef __attribute__((ext_vector_type(8))) short bf16x8;
typedef __attribute__((ext_vector_type(4))) float f32x4;

static __device__ __forceinline__ unsigned int f2bf(float f) {
    unsigned int u = __float_as_uint(f);
    u = u + 0x7FFFu + ((u >> 16) & 1u);   // RNE; inputs are finite
    return (u >> 16);
}

static __device__ __forceinline__ float fast_tanh(float x) {
    x = fminf(fmaxf(x, -10.f), 10.f);
    float e = __expf(2.f * x);
    return __fdividef(e - 1.f, e + 1.f);
}

// LDS-only barrier: global stores are NOT drained (vmcnt untouched).
#define LGKM_BAR() do {                                      \
    asm volatile("s_waitcnt lgkmcnt(0)" ::: "memory");       \
    __builtin_amdgcn_s_barrier();                            \
} while (0)

// Wave-local LDS drain (no barrier).
#define LGKM_WAIT() asm volatile("s_waitcnt lgkmcnt(0)" ::: "memory")

// ---------------- prep: weight transposes into ws + fci_w2 permute->bf16
__global__ __launch_bounds__(256)
void prep(const float* __restrict__ fc_w, const float* __restrict__ inp_w,
          const float* __restrict__ outp_w, const float* __restrict__ fci_w1,
          const float* __restrict__ fcn_w, const float* __restrict__ fci_w2,
          float* __restrict__ fcwT, float* __restrict__ inpT,
          float* __restrict__ outpT, float* __restrict__ waT,
          float* __restrict__ wbT, float* __restrict__ fcnT,
          uint4* __restrict__ w2p)
{
    const int idx0 = blockIdx.x * 256 + threadIdx.x;
    const int stride = 64 * 256;
    switch (blockIdx.y) {
    case 0:
        for (int c = idx0; c < 32768; c += stride) {
            int k = c >> 8, n = c & 255;
            fcwT[c] = fc_w[n * 128 + k];
        }
        break;
    case 1:
        for (int c = idx0; c < 196608; c += stride) {
            int k = c / 768, n = c - k * 768;
            inpT[c] = inp_w[n * 256 + k];
        }
        break;
    case 2:
        for (int c = idx0; c < 65536; c += stride) {
            int k = c >> 8, n = c & 255;
            outpT[c] = outp_w[n * 256 + k];
        }
        break;
    case 3:
        for (int c = idx0; c < 65536; c += stride) {
            int k = c >> 8, n = c & 255;
            waT[c] = fci_w1[n * 512 + k];
        }
        break;
    case 4:
        for (int c = idx0; c < 65536; c += stride) {
            int k = c >> 8, n = c & 255;
            wbT[c] = fci_w1[n * 512 + 256 + k];
        }
        break;
    case 5:
        for (int c = idx0; c < 20480; c += stride) {
            int k = c / 80, n = c - k * 80;
            fcnT[c] = fcn_w[n * 256 + k];
        }
        break;
    default:
        for (int c = idx0; c < 25600; c += stride) {
            const int n_g = c >> 5, e = c & 31;
            const int kk = e >> 2, kg = e & 3;
            const int ph = (n_g >= 400) ? 1 : 0;
            const int n = n_g - ph * 400;
            const float4* s = (const float4*)(fci_w2 + n_g * 256 + kk * 32 + kg * 8);
            const float4 x0 = s[0], x1 = s[1];
            uint4 pk;
            pk.x = f2bf(x0.x) | (f2bf(x0.y) << 16);
            pk.y = f2bf(x0.z) | (f2bf(x0.w) << 16);
            pk.z = f2bf(x1.x) | (f2bf(x1.y) << 16);
            pk.w = f2bf(x1.z) | (f2bf(x1.w) << 16);
            w2p[((ph * 8 + kk) * 400 + n) * 4 + kg] = pk;
        }
        break;
    }
}

// ---------------- k1: grid (384, 3). Block (i, part): recompute h1row (bitwise-
// identical across parts), then qkv[i, part*256 .. +256]. 1152 blocks -> 4.5/CU.
__global__ __launch_bounds__(256)
void k1_rows(const float* __restrict__ h, const float* __restrict__ fc_b,
             const float* __restrict__ inp_b, const float* __restrict__ fcwT,
             const float* __restrict__ inpT, float* __restrict__ qkv)
{
    __shared__ float hrow[128];
    __shared__ float h1row[256];
    const int i = blockIdx.x, part = blockIdx.y, tid = threadIdx.x;
    if (tid < 128) hrow[tid] = h[i * 128 + tid];
    __syncthreads();
    float acc = fc_b[tid];
    #pragma unroll 8
    for (int k = 0; k < 128; ++k) acc += hrow[k] * fcwT[k * 256 + tid];
    h1row[tid] = acc;
    __syncthreads();
    const int col = part * 256 + tid;
    float a = inp_b[col];
    #pragma unroll 8
    for (int k = 0; k < 256; ++k) a += h1row[k] * inpT[k * 768 + col];
    qkv[i * 768 + col] = a;
}

// ---------------- attention: one block per (row n, head h). 8 heads, HEAD_D=32.
__global__ __launch_bounds__(256)
void attn_kernel(const float* __restrict__ qkv, float* __restrict__ out)
{
    const int n = blockIdx.x;
    const int h = blockIdx.y;
    const int tid = threadIdx.x;
    const int lane = tid & 63;
    const int wid = tid >> 6;

    __shared__ float qs[32];
    __shared__ float p[384];
    __shared__ float red[8];
    __shared__ float pv[8][32];

    if (tid < 32) qs[tid] = qkv[n * 768 + h * 32 + tid] * 0.17677669529663687f;
    __syncthreads();

    float lmax = -1e30f;
    for (int m = tid; m < 384; m += 256) {
        const float4* kr = (const float4*)(qkv + m * 768 + 256 + h * 32);
        float s = 0.f;
        #pragma unroll
        for (int d = 0; d < 8; ++d) {
            float4 kv = kr[d];
            s += qs[d*4+0]*kv.x + qs[d*4+1]*kv.y + qs[d*4+2]*kv.z + qs[d*4+3]*kv.w;
        }
        p[m] = s;
        lmax = fmaxf(lmax, s);
    }
    #pragma unroll
    for (int off = 32; off >= 1; off >>= 1) lmax = fmaxf(lmax, __shfl_xor(lmax, off));
    if (lane == 0) red[wid] = lmax;
    __syncthreads();
    const float gmax = fmaxf(fmaxf(red[0], red[1]), fmaxf(red[2], red[3]));

    float lsum = 0.f;
    for (int m = tid; m < 384; m += 256) {
        float e = __expf(p[m] - gmax);
        p[m] = e;
        lsum += e;
    }
    #pragma unroll
    for (int off = 32; off >= 1; off >>= 1) lsum += __shfl_xor(lsum, off);
    if (lane == 0) red[4 + wid] = lsum;
    __syncthreads();
    const float inv = 1.f / (red[4] + red[5] + red[6] + red[7]);

    const int d = tid & 31;
    const int g = tid >> 5;
    float acc = 0.f;
    for (int m = g * 48; m < g * 48 + 48; ++m)
        acc += p[m] * qkv[m * 768 + 512 + h * 32 + d];
    pv[g][d] = acc;
    __syncthreads();
    if (tid < 32) {
        float o = 0.f;
        #pragma unroll
        for (int gg = 0; gg < 8; ++gg) o += pv[gg][tid];
        out[n * 256 + h * 32 + tid] = o * inv;
    }
}

// ---------------- k3: grid (384, 3). Block (i, part): recompute h2row (bitwise-
// identical), then part 0: hA, part 1: hB, part 2: node+scatter. 1152 blocks.
__global__ __launch_bounds__(256)
void k3_rows(const float* __restrict__ attnO, const float* __restrict__ outp_b,
             const float* __restrict__ fci_b1, const float* __restrict__ fcn_b,
             const float* __restrict__ outpT, const float* __restrict__ waT,
             const float* __restrict__ wbT, const float* __restrict__ fcnT,
             float* __restrict__ hA, float* __restrict__ hB, float* __restrict__ out)
{
    __shared__ float arow[256];
    __shared__ float h2row[256];
    const int i = blockIdx.x, part = blockIdx.y, tid = threadIdx.x;
    arow[tid] = attnO[i * 256 + tid];
    __syncthreads();
    float acc = outp_b[tid];
    #pragma unroll 8
    for (int k = 0; k < 256; ++k) acc += arow[k] * outpT[k * 256 + tid];
    h2row[tid] = acc;
    __syncthreads();
    if (part == 0) {
        float aA = fci_b1[tid];
        #pragma unroll 8
        for (int k = 0; k < 256; ++k) aA += h2row[k] * waT[k * 256 + tid];
        hA[i * 256 + tid] = aA;
    } else if (part == 1) {
        float aB = 0.f;
        #pragma unroll 8
        for (int k = 0; k < 256; ++k) aB += h2row[k] * wbT[k * 256 + tid];
        hB[i * 256 + tid] = aB;
    } else if (tid < 80) {
        float aN = fcn_b[tid];
        #pragma unroll 8
        for (int k = 0; k < 256; ++k) aN += h2row[k] * fcnT[k * 80 + tid];
        if (tid < 64)      out[117964800 + i * 64 + tid] = aN;
        else if (tid < 72) out[117989376 + i * 8 + (tid - 64)] = aN;
        else               out[117992448 + i * 8 + (tid - 72)] = aN;
    }
}

// ---------------- gen_kq v16: BM=96 (B re-read traffic halved: 1.2GB -> 0.6GB).
// Theory under test: the ~2.9TB/s plateau is L2/L3 read-write contention — the
// write stream evicts w2p from each XCD L2, pushing 7.3TB/s of B-reads to L3 on
// top of the write traffic. BM=96 halves grid-wide B-reads. Per wave: acc[6][5]
// (120 VGPR, no launch-bounds cap -> no spill; 512/wave file). LDS 48+26.25KB
// -> 2 blocks/CU. Epilogue/store path byte-identical to v8 (measured best).
#define CSW_ROWB 336   // 80 f32 + 16B pad

__global__ __launch_bounds__(320)
void gen_kq(const float* __restrict__ hA, const float* __restrict__ hB,
            const uint4* __restrict__ w2p, const float* __restrict__ b2,
            float* __restrict__ outK, float* __restrict__ outQ)
{
    __shared__ unsigned char Aim[96 * 512];            // 48 KB, XOR-swizzled
    __shared__ unsigned char Csw[5][16 * CSW_ROWB];    // 26.25 KB, per-wave slices

    const int tid  = threadIdx.x;
    const int lane = tid & 63;
    const int wn   = tid >> 6;          // 0..4  (80-col fifth)
    const int lr   = lane & 15;
    const int kg   = lane >> 4;

    // XCD-chunked swizzle: grid 1536 = 8 XCDs x 192 contiguous blocks each.
    const int bid0 = blockIdx.x;
    const int bid  = (bid0 & 7) * 192 + (bid0 >> 3);

    const int m0  = bid * 96;
    const int ai  = bid >> 2;           // exact: 384 = 4*96
    const int bj0 = (bid & 3) * 96;

    // ---- A image: tanh(hA[bj0+row] + hB[ai]) -> bf16, 3072 cells of 16B
    for (int c = tid; c < 3072; c += 320) {
        const int row = c >> 5;
        const int e   = c & 31;
        const int ke  = e * 8;
        const float4 a0 = *(const float4*)(hA + (bj0 + row) * 256 + ke);
        const float4 a1 = *(const float4*)(hA + (bj0 + row) * 256 + ke + 4);
        const float4 b0 = *(const float4*)(hB + ai * 256 + ke);
        const float4 b1 = *(const float4*)(hB + ai * 256 + ke + 4);
        uint4 pk;
        pk.x = f2bf(fast_tanh(a0.x + b0.x)) | (f2bf(fast_tanh(a0.y + b0.y)) << 16);
        pk.y = f2bf(fast_tanh(a0.z + b0.z)) | (f2bf(fast_tanh(a0.w + b0.w)) << 16);
        pk.z = f2bf(fast_tanh(a1.x + b1.x)) | (f2bf(fast_tanh(a1.y + b1.y)) << 16);
        pk.w = f2bf(fast_tanh(a1.z + b1.z)) | (f2bf(fast_tanh(a1.w + b1.w)) << 16);
        *(uint4*)(Aim + row * 512 + ((e * 16) ^ ((row & 7) << 4))) = pk;
    }
    LGKM_BAR();

    const int phfirst = bid & 1;        // parity stagger: half the blocks do Q first
    #pragma unroll
    for (int pp = 0; pp < 2; ++pp) {
        const int ph = pp ^ phfirst;    // uniform per block

        // ---- acc init = bias (cols n = wn*80 + j*16 + kg*4 + reg)
        f32x4 acc[6][5];
        #pragma unroll
        for (int j = 0; j < 5; ++j) {
            const f32x4 bb = *(const f32x4*)(b2 + ph * 400 + wn * 80 + j * 16 + kg * 4);
            #pragma unroll
            for (int i = 0; i < 6; ++i)
                acc[i][j] = bb;
        }

        // ---- K-loop: no barriers. A from LDS, B direct from L2 (read ONCE per
        // block for 96 output rows instead of 48).
        #pragma unroll 2
        for (int kk = 0; kk < 8; ++kk) {
            bf16x8 af_[6], bf_[5];
            const uint4* wb = w2p + (ph * 8 + kk) * 1600;
            #pragma unroll
            for (int j = 0; j < 5; ++j)
                bf_[j] = *(const bf16x8*)(wb + (wn * 80 + j * 16 + lr) * 4 + kg);
            #pragma unroll
            for (int i = 0; i < 6; ++i) {
                const int row = i * 16 + lr;
                af_[i] = *(const bf16x8*)(Aim + row * 512 +
                          ((kk * 64 + kg * 16) ^ ((row & 7) << 4)));
            }
            #pragma unroll
            for (int i = 0; i < 6; ++i)
                #pragma unroll
                for (int j = 0; j < 5; ++j)
                    acc[i][j] = __builtin_amdgcn_mfma_f32_16x16x32_bf16(
                        bf_[j], af_[i], acc[i][j], 0, 0, 0);
        }

        // ---- epilogue: per-wave transpose through private slice; NO barriers.
        float* gob = ph ? outQ : outK;
        unsigned char* slice = Csw[wn];
        #pragma unroll
        for (int i = 0; i < 6; ++i) {
            #pragma unroll
            for (int j = 0; j < 5; ++j)
                *(f32x4*)(slice + lr * CSW_ROWB + (j * 16 + kg * 4) * 4) = acc[i][j];
            LGKM_WAIT();                // wave-local: ds_writes visible to own reads
            float* gb = gob + (size_t)(m0 + i * 16) * 400 + wn * 80;
            #pragma unroll
            for (int q = 0; q < 5; ++q) {
                const int e   = q * 64 + lane;      // 0..319
                const int row = e / 20, c4 = e - row * 20;
                const f32x4 v = *(const f32x4*)(slice + row * CSW_ROWB + c4 * 16);
                *(f32x4*)(gb + row * 400 + c4 * 4) = v;   // cached store, 320B runs
            }
        }
    }
}

extern "C" void kernel_launch(void* const* d_in, const int* in_sizes, int n_in,
                              void* d_out, int out_size, void* d_ws, size_t ws_size,
                              hipStream_t stream)
{
    (void)in_sizes; (void)n_in; (void)out_size; (void)ws_size;

    const float* h      = (const float*)d_in[0];
    const float* fc_w   = (const float*)d_in[1];
    const float* fc_b   = (const float*)d_in[2];
    const float* inp_w  = (const float*)d_in[3];
    const float* inp_b  = (const float*)d_in[4];
    const float* outp_w = (const float*)d_in[5];
    const float* outp_b = (const float*)d_in[6];
    const float* fci_w1 = (const float*)d_in[7];
    const float* fci_b1 = (const float*)d_in[8];
    const float* fci_w2 = (const float*)d_in[9];
    const float* fci_b2 = (const float*)d_in[10];
    const float* fcn_w  = (const float*)d_in[11];
    const float* fcn_b  = (const float*)d_in[12];

    float* out  = (float*)d_out;
    float* outK = out;
    float* outQ = out + 58982400;   // 384*384*400

    float* ws    = (float*)d_ws;
    float* qkv   = ws;                       // 294912
    float* attnO = qkv   + 294912;           // 98304
    float* hA    = attnO + 98304;            // 98304 (b1 folded in)
    float* hBv   = hA    + 98304;            // 98304
    float* fcwT  = hBv   + 98304;            // 32768
    float* inpT  = fcwT  + 32768;            // 196608
    float* outpT = inpT  + 196608;           // 65536
    float* waT   = outpT + 65536;            // 65536
    float* wbT   = waT   + 65536;            // 65536
    float* fcnT  = wbT   + 65536;            // 20480
    uint4* w2p   = (uint4*)(fcnT + 20480);   // 409600 B, 16B-aligned

    prep<<<dim3(64, 7), 256, 0, stream>>>(fc_w, inp_w, outp_w, fci_w1, fcn_w, fci_w2,
                                          fcwT, inpT, outpT, waT, wbT, fcnT, w2p);
    k1_rows<<<dim3(384, 3), 256, 0, stream>>>(h, fc_b, inp_b, fcwT, inpT, qkv);
    attn_kernel<<<dim3(384, 8), 256, 0, stream>>>(qkv, attnO);
    k3_rows<<<dim3(384, 3), 256, 0, stream>>>(attnO, outp_b, fci_b1, fcn_b, outpT, waT, wbT, fcnT,
                                              hA, hBv, out);
    gen_kq<<<dim3(1536), 320, 0, stream>>>(hA, hBv, w2p, fci_b2, outK, outQ);
}

// Round 18
// 221.782 us; speedup vs baseline: 1.1561x; 1.1561x over previous
//
#include <hip/hip_runtime.h>
#include <hip/hip_bf16.h>

typedef __attribute__((ext_vector_type(8))) short bf16x8;
typedef __attribute__((ext_vector_type(4))) float f32x4;

static __device__ __forceinline__ unsigned int f2bf(float f) {
    unsigned int u = __float_as_uint(f);
    u = u + 0x7FFFu + ((u >> 16) & 1u);   // RNE; inputs are finite
    return (u >> 16);
}

static __device__ __forceinline__ float fast_tanh(float x) {
    x = fminf(fmaxf(x, -10.f), 10.f);
    float e = __expf(2.f * x);
    return __fdividef(e - 1.f, e + 1.f);
}

// LDS-only barrier: global stores are NOT drained (vmcnt untouched).
#define LGKM_BAR() do {                                      \
    asm volatile("s_waitcnt lgkmcnt(0)" ::: "memory");       \
    __builtin_amdgcn_s_barrier();                            \
} while (0)

// Wave-local LDS drain (no barrier).
#define LGKM_WAIT() asm volatile("s_waitcnt lgkmcnt(0)" ::: "memory")

// ---------------- prep: weight transposes into ws + fci_w2 permute->bf16
__global__ __launch_bounds__(256)
void prep(const float* __restrict__ fc_w, const float* __restrict__ inp_w,
          const float* __restrict__ outp_w, const float* __restrict__ fci_w1,
          const float* __restrict__ fcn_w, const float* __restrict__ fci_w2,
          float* __restrict__ fcwT, float* __restrict__ inpT,
          float* __restrict__ outpT, float* __restrict__ waT,
          float* __restrict__ wbT, float* __restrict__ fcnT,
          uint4* __restrict__ w2p)
{
    const int idx0 = blockIdx.x * 256 + threadIdx.x;
    const int stride = 64 * 256;
    switch (blockIdx.y) {
    case 0:
        for (int c = idx0; c < 32768; c += stride) {
            int k = c >> 8, n = c & 255;
            fcwT[c] = fc_w[n * 128 + k];
        }
        break;
    case 1:
        for (int c = idx0; c < 196608; c += stride) {
            int k = c / 768, n = c - k * 768;
            inpT[c] = inp_w[n * 256 + k];
        }
        break;
    case 2:
        for (int c = idx0; c < 65536; c += stride) {
            int k = c >> 8, n = c & 255;
            outpT[c] = outp_w[n * 256 + k];
        }
        break;
    case 3:
        for (int c = idx0; c < 65536; c += stride) {
            int k = c >> 8, n = c & 255;
            waT[c] = fci_w1[n * 512 + k];
        }
        break;
    case 4:
        for (int c = idx0; c < 65536; c += stride) {
            int k = c >> 8, n = c & 255;
            wbT[c] = fci_w1[n * 512 + 256 + k];
        }
        break;
    case 5:
        for (int c = idx0; c < 20480; c += stride) {
            int k = c / 80, n = c - k * 80;
            fcnT[c] = fcn_w[n * 256 + k];
        }
        break;
    default:
        for (int c = idx0; c < 25600; c += stride) {
            const int n_g = c >> 5, e = c & 31;
            const int kk = e >> 2, kg = e & 3;
            const int ph = (n_g >= 400) ? 1 : 0;
            const int n = n_g - ph * 400;
            const float4* s = (const float4*)(fci_w2 + n_g * 256 + kk * 32 + kg * 8);
            const float4 x0 = s[0], x1 = s[1];
            uint4 pk;
            pk.x = f2bf(x0.x) | (f2bf(x0.y) << 16);
            pk.y = f2bf(x0.z) | (f2bf(x0.w) << 16);
            pk.z = f2bf(x1.x) | (f2bf(x1.y) << 16);
            pk.w = f2bf(x1.z) | (f2bf(x1.w) << 16);
            w2p[((ph * 8 + kk) * 400 + n) * 4 + kg] = pk;
        }
        break;
    }
}

// ---------------- k1: grid (384, 3). Block (i, part): recompute h1row (bitwise-
// identical across parts), then qkv[i, part*256 .. +256]. 1152 blocks -> 4.5/CU.
__global__ __launch_bounds__(256)
void k1_rows(const float* __restrict__ h, const float* __restrict__ fc_b,
             const float* __restrict__ inp_b, const float* __restrict__ fcwT,
             const float* __restrict__ inpT, float* __restrict__ qkv)
{
    __shared__ float hrow[128];
    __shared__ float h1row[256];
    const int i = blockIdx.x, part = blockIdx.y, tid = threadIdx.x;
    if (tid < 128) hrow[tid] = h[i * 128 + tid];
    __syncthreads();
    float acc = fc_b[tid];
    #pragma unroll 8
    for (int k = 0; k < 128; ++k) acc += hrow[k] * fcwT[k * 256 + tid];
    h1row[tid] = acc;
    __syncthreads();
    const int col = part * 256 + tid;
    float a = inp_b[col];
    #pragma unroll 8
    for (int k = 0; k < 256; ++k) a += h1row[k] * inpT[k * 768 + col];
    qkv[i * 768 + col] = a;
}

// ---------------- attention: one block per (row n, head h). 8 heads, HEAD_D=32.
__global__ __launch_bounds__(256)
void attn_kernel(const float* __restrict__ qkv, float* __restrict__ out)
{
    const int n = blockIdx.x;
    const int h = blockIdx.y;
    const int tid = threadIdx.x;
    const int lane = tid & 63;
    const int wid = tid >> 6;

    __shared__ float qs[32];
    __shared__ float p[384];
    __shared__ float red[8];
    __shared__ float pv[8][32];

    if (tid < 32) qs[tid] = qkv[n * 768 + h * 32 + tid] * 0.17677669529663687f;
    __syncthreads();

    float lmax = -1e30f;
    for (int m = tid; m < 384; m += 256) {
        const float4* kr = (const float4*)(qkv + m * 768 + 256 + h * 32);
        float s = 0.f;
        #pragma unroll
        for (int d = 0; d < 8; ++d) {
            float4 kv = kr[d];
            s += qs[d*4+0]*kv.x + qs[d*4+1]*kv.y + qs[d*4+2]*kv.z + qs[d*4+3]*kv.w;
        }
        p[m] = s;
        lmax = fmaxf(lmax, s);
    }
    #pragma unroll
    for (int off = 32; off >= 1; off >>= 1) lmax = fmaxf(lmax, __shfl_xor(lmax, off));
    if (lane == 0) red[wid] = lmax;
    __syncthreads();
    const float gmax = fmaxf(fmaxf(red[0], red[1]), fmaxf(red[2], red[3]));

    float lsum = 0.f;
    for (int m = tid; m < 384; m += 256) {
        float e = __expf(p[m] - gmax);
        p[m] = e;
        lsum += e;
    }
    #pragma unroll
    for (int off = 32; off >= 1; off >>= 1) lsum += __shfl_xor(lsum, off);
    if (lane == 0) red[4 + wid] = lsum;
    __syncthreads();
    const float inv = 1.f / (red[4] + red[5] + red[6] + red[7]);

    const int d = tid & 31;
    const int g = tid >> 5;
    float acc = 0.f;
    for (int m = g * 48; m < g * 48 + 48; ++m)
        acc += p[m] * qkv[m * 768 + 512 + h * 32 + d];
    pv[g][d] = acc;
    __syncthreads();
    if (tid < 32) {
        float o = 0.f;
        #pragma unroll
        for (int gg = 0; gg < 8; ++gg) o += pv[gg][tid];
        out[n * 256 + h * 32 + tid] = o * inv;
    }
}

// ---------------- k3: grid (384, 3). Block (i, part): recompute h2row (bitwise-
// identical), then part 0: hA, part 1: hB, part 2: node+scatter. 1152 blocks.
__global__ __launch_bounds__(256)
void k3_rows(const float* __restrict__ attnO, const float* __restrict__ outp_b,
             const float* __restrict__ fci_b1, const float* __restrict__ fcn_b,
             const float* __restrict__ outpT, const float* __restrict__ waT,
             const float* __restrict__ wbT, const float* __restrict__ fcnT,
             float* __restrict__ hA, float* __restrict__ hB, float* __restrict__ out)
{
    __shared__ float arow[256];
    __shared__ float h2row[256];
    const int i = blockIdx.x, part = blockIdx.y, tid = threadIdx.x;
    arow[tid] = attnO[i * 256 + tid];
    __syncthreads();
    float acc = outp_b[tid];
    #pragma unroll 8
    for (int k = 0; k < 256; ++k) acc += arow[k] * outpT[k * 256 + tid];
    h2row[tid] = acc;
    __syncthreads();
    if (part == 0) {
        float aA = fci_b1[tid];
        #pragma unroll 8
        for (int k = 0; k < 256; ++k) aA += h2row[k] * waT[k * 256 + tid];
        hA[i * 256 + tid] = aA;
    } else if (part == 1) {
        float aB = 0.f;
        #pragma unroll 8
        for (int k = 0; k < 256; ++k) aB += h2row[k] * wbT[k * 256 + tid];
        hB[i * 256 + tid] = aB;
    } else if (tid < 80) {
        float aN = fcn_b[tid];
        #pragma unroll 8
        for (int k = 0; k < 256; ++k) aN += h2row[k] * fcnT[k * 80 + tid];
        if (tid < 64)      out[117964800 + i * 64 + tid] = aN;
        else if (tid < 72) out[117989376 + i * 8 + (tid - 64)] = aN;
        else               out[117992448 + i * 8 + (tid - 72)] = aN;
    }
}

// ---------------- gen_kq v8 (measured best, 164us): A-image LDS, B direct from
// L2, per-wave private Csw transpose, 320B-run cached stores, zero epilogue
// barriers, XCD-chunked bids, K/Q parity stagger. BYTE-IDENTICAL to round 9.
#define CSW_ROWB 336   // 80 f32 + 16B pad

__global__ __launch_bounds__(320)
void gen_kq(const float* __restrict__ hA, const float* __restrict__ hB,
            const uint4* __restrict__ w2p, const float* __restrict__ b2,
            float* __restrict__ outK, float* __restrict__ outQ)
{
    __shared__ unsigned char Aim[48 * 512];            // 24 KB, XOR-swizzled
    __shared__ unsigned char Csw[5][16 * CSW_ROWB];    // 26.25 KB, per-wave slices

    const int tid  = threadIdx.x;
    const int lane = tid & 63;
    const int wn   = tid >> 6;          // 0..4  (80-col fifth)
    const int lr   = lane & 15;
    const int kg   = lane >> 4;

    // XCD-chunked swizzle: grid 3072 = 8 XCDs x 384 contiguous blocks each.
    const int bid0 = blockIdx.x;
    const int bid  = (bid0 & 7) * 384 + (bid0 >> 3);

    const int m0  = bid * 48;
    const int ai  = bid >> 3;           // exact: 384 = 8*48
    const int bj0 = (bid & 7) * 48;

    // ---- A image: tanh(hA[bj0+row] + hB[ai]) -> bf16, 1536 cells of 16B
    for (int c = tid; c < 1536; c += 320) {
        const int row = c >> 5;
        const int e   = c & 31;
        const int ke  = e * 8;
        const float4 a0 = *(const float4*)(hA + (bj0 + row) * 256 + ke);
        const float4 a1 = *(const float4*)(hA + (bj0 + row) * 256 + ke + 4);
        const float4 b0 = *(const float4*)(hB + ai * 256 + ke);
        const float4 b1 = *(const float4*)(hB + ai * 256 + ke + 4);
        uint4 pk;
        pk.x = f2bf(fast_tanh(a0.x + b0.x)) | (f2bf(fast_tanh(a0.y + b0.y)) << 16);
        pk.y = f2bf(fast_tanh(a0.z + b0.z)) | (f2bf(fast_tanh(a0.w + b0.w)) << 16);
        pk.z = f2bf(fast_tanh(a1.x + b1.x)) | (f2bf(fast_tanh(a1.y + b1.y)) << 16);
        pk.w = f2bf(fast_tanh(a1.z + b1.z)) | (f2bf(fast_tanh(a1.w + b1.w)) << 16);
        *(uint4*)(Aim + row * 512 + ((e * 16) ^ ((row & 7) << 4))) = pk;
    }
    LGKM_BAR();

    const int phfirst = bid & 1;        // parity stagger: half the blocks do Q first
    #pragma unroll
    for (int pp = 0; pp < 2; ++pp) {
        const int ph = pp ^ phfirst;    // uniform per block

        // ---- acc init = bias (cols n = wn*80 + j*16 + kg*4 + reg)
        f32x4 acc[3][5];
        #pragma unroll
        for (int j = 0; j < 5; ++j) {
            const f32x4 bb = *(const f32x4*)(b2 + ph * 400 + wn * 80 + j * 16 + kg * 4);
            #pragma unroll
            for (int i = 0; i < 3; ++i)
                acc[i][j] = bb;
        }

        // ---- K-loop: no barriers. A from LDS, B direct from L2.
        #pragma unroll 2
        for (int kk = 0; kk < 8; ++kk) {
            bf16x8 af_[3], bf_[5];
            const uint4* wb = w2p + (ph * 8 + kk) * 1600;
            #pragma unroll
            for (int j = 0; j < 5; ++j)
                bf_[j] = *(const bf16x8*)(wb + (wn * 80 + j * 16 + lr) * 4 + kg);
            #pragma unroll
            for (int i = 0; i < 3; ++i) {
                const int row = i * 16 + lr;
                af_[i] = *(const bf16x8*)(Aim + row * 512 +
                          ((kk * 64 + kg * 16) ^ ((row & 7) << 4)));
            }
            #pragma unroll
            for (int i = 0; i < 3; ++i)
                #pragma unroll
                for (int j = 0; j < 5; ++j)
                    acc[i][j] = __builtin_amdgcn_mfma_f32_16x16x32_bf16(
                        bf_[j], af_[i], acc[i][j], 0, 0, 0);
        }

        // ---- epilogue: per-wave transpose through private slice; NO barriers.
        float* gob = ph ? outQ : outK;
        unsigned char* slice = Csw[wn];
        #pragma unroll
        for (int i = 0; i < 3; ++i) {
            #pragma unroll
            for (int j = 0; j < 5; ++j)
                *(f32x4*)(slice + lr * CSW_ROWB + (j * 16 + kg * 4) * 4) = acc[i][j];
            LGKM_WAIT();                // wave-local: ds_writes visible to own reads
            float* gb = gob + (size_t)(m0 + i * 16) * 400 + wn * 80;
            #pragma unroll
            for (int q = 0; q < 5; ++q) {
                const int e   = q * 64 + lane;      // 0..319
                const int row = e / 20, c4 = e - row * 20;
                const f32x4 v = *(const f32x4*)(slice + row * CSW_ROWB + c4 * 16);
                *(f32x4*)(gb + row * 400 + c4 * 4) = v;   // cached store, 320B runs
            }
        }
    }
}

extern "C" void kernel_launch(void* const* d_in, const int* in_sizes, int n_in,
                              void* d_out, int out_size, void* d_ws, size_t ws_size,
                              hipStream_t stream)
{
    (void)in_sizes; (void)n_in; (void)out_size; (void)ws_size;

    const float* h      = (const float*)d_in[0];
    const float* fc_w   = (const float*)d_in[1];
    const float* fc_b   = (const float*)d_in[2];
    const float* inp_w  = (const float*)d_in[3];
    const float* inp_b  = (const float*)d_in[4];
    const float* outp_w = (const float*)d_in[5];
    const float* outp_b = (const float*)d_in[6];
    const float* fci_w1 = (const float*)d_in[7];
    const float* fci_b1 = (const float*)d_in[8];
    const float* fci_w2 = (const float*)d_in[9];
    const float* fci_b2 = (const float*)d_in[10];
    const float* fcn_w  = (const float*)d_in[11];
    const float* fcn_b  = (const float*)d_in[12];

    float* out  = (float*)d_out;
    float* outK = out;
    float* outQ = out + 58982400;   // 384*384*400

    float* ws    = (float*)d_ws;
    float* qkv   = ws;                       // 294912
    float* attnO = qkv   + 294912;           // 98304
    float* hA    = attnO + 98304;            // 98304 (b1 folded in)
    float* hBv   = hA    + 98304;            // 98304
    float* fcwT  = hBv   + 98304;            // 32768
    float* inpT  = fcwT  + 32768;            // 196608
    float* outpT = inpT  + 196608;           // 65536
    float* waT   = outpT + 65536;            // 65536
    float* wbT   = waT   + 65536;            // 65536
    float* fcnT  = wbT   + 65536;            // 20480
    uint4* w2p   = (uint4*)(fcnT + 20480);   // 409600 B, 16B-aligned

    prep<<<dim3(64, 7), 256, 0, stream>>>(fc_w, inp_w, outp_w, fci_w1, fcn_w, fci_w2,
                                          fcwT, inpT, outpT, waT, wbT, fcnT, w2p);
    k1_rows<<<dim3(384, 3), 256, 0, stream>>>(h, fc_b, inp_b, fcwT, inpT, qkv);
    attn_kernel<<<dim3(384, 8), 256, 0, stream>>>(qkv, attnO);
    k3_rows<<<dim3(384, 3), 256, 0, stream>>>(attnO, outp_b, fci_b1, fcn_b, outpT, waT, wbT, fcnT,
                                              hA, hBv, out);
    gen_kq<<<dim3(3072), 320, 0, stream>>>(hA, hBv, w2p, fci_b2, outK, outQ);
}